// Round 10
// baseline (20689.145 us; speedup 1.0000x reference)
//
#include <hip/hip_runtime.h>
#include <math.h>

#define F_DIM 128
#define EMB 300
#define HID 512
#define NSTEP 4096
#define NNBR 64
#define GWGS 32   // workgroups per recurrent group (F and L)
#define NREP 4    // replication of published vectors (pollers per line: 8)
#define LSTR 36   // LDS row stride (floats) — 16-lane teams => broadcast reads, 0 conflicts

typedef unsigned long long ull;

__device__ __forceinline__ float sigmf(float x){ return 1.0f/(1.0f + expf(-x)); }

__device__ __forceinline__ float red16(float v){
  v += __shfl_xor(v, 8);
  v += __shfl_xor(v, 4);
  v += __shfl_xor(v, 2);
  v += __shfl_xor(v, 1);
  return v;
}

// poll 4 consecutive packed {tag<<32|val} words until all tags match; deposit to LDS
// as two float2 (R7's proven conflict-free pattern). Dependent tag-checked loop only —
// no early samples, no asm (R5/R9 lesson).
__device__ __forceinline__ void poll4(const ull* __restrict__ p, unsigned tag,
                                      float* __restrict__ lds){
  ull a, b, c, d;
  for(;;){
    a = __hip_atomic_load(p,   __ATOMIC_RELAXED, __HIP_MEMORY_SCOPE_AGENT);
    b = __hip_atomic_load(p+1, __ATOMIC_RELAXED, __HIP_MEMORY_SCOPE_AGENT);
    c = __hip_atomic_load(p+2, __ATOMIC_RELAXED, __HIP_MEMORY_SCOPE_AGENT);
    d = __hip_atomic_load(p+3, __ATOMIC_RELAXED, __HIP_MEMORY_SCOPE_AGENT);
    unsigned bad = (((unsigned)(a>>32)) ^ tag) | (((unsigned)(b>>32)) ^ tag)
                 | (((unsigned)(c>>32)) ^ tag) | (((unsigned)(d>>32)) ^ tag);
    if (bad == 0u) break;
  }
  *(float2*)(lds)     = make_float2(__uint_as_float((unsigned)a), __uint_as_float((unsigned)b));
  *(float2*)(lds + 2) = make_float2(__uint_as_float((unsigned)c), __uint_as_float((unsigned)d));
}

// ---------------- generic tiled f32 GEMM: C[M,N] = A[M,K]@B[K,N] (+D) (+bias_n) ----
__global__ void gemm_tiled(const float* __restrict__ A, int lda,
                           const float* __restrict__ B, int ldb, int transB,
                           const float* __restrict__ D, int ldd,
                           const float* __restrict__ bias,
                           float* __restrict__ C, int ldc,
                           int M, int N, int K)
{
  __shared__ float As[16][65];
  __shared__ float Bs[16][65];
  const int tid = threadIdx.x;
  const int m0 = blockIdx.y*64, n0 = blockIdx.x*64;
  const int ty = tid>>4, tx = tid&15;
  float acc[4][4] = {};
  for (int k0=0; k0<K; k0+=16){
    #pragma unroll
    for (int i=0;i<4;i++){
      int idx = tid + i*256;
      int m = idx>>4, k = idx&15;
      float va = 0.f;
      if (m0+m < M && k0+k < K) va = A[(size_t)(m0+m)*lda + k0+k];
      As[k][m] = va;
      int k2 = idx>>6, n = idx&63;
      float vb = 0.f;
      if (k0+k2 < K && n0+n < N)
        vb = transB ? B[(size_t)(n0+n)*ldb + k0+k2] : B[(size_t)(k0+k2)*ldb + n0+n];
      Bs[k2][n] = vb;
    }
    __syncthreads();
    #pragma unroll
    for (int k=0;k<16;k++){
      float a[4], b[4];
      #pragma unroll
      for (int i=0;i<4;i++) a[i] = As[k][ty*4+i];
      #pragma unroll
      for (int j=0;j<4;j++) b[j] = Bs[k][tx*4+j];
      #pragma unroll
      for (int i=0;i<4;i++)
        #pragma unroll
        for (int j=0;j<4;j++) acc[i][j] += a[i]*b[j];
    }
    __syncthreads();
  }
  #pragma unroll
  for (int i=0;i<4;i++){
    int m = m0 + ty*4 + i;
    if (m >= M) continue;
    #pragma unroll
    for (int j=0;j<4;j++){
      int n = n0 + tx*4 + j;
      if (n >= N) continue;
      float v = acc[i][j];
      if (D)    v += D[(size_t)m*ldd + n];
      if (bias) v += bias[n];
      C[(size_t)m*ldc + n] = v;
    }
  }
}

// ---------------- matvec: out[m] = sum_k A[m,k]*x[k] (+bias[m]); transA reads A[k,m]
__global__ void matvec(const float* __restrict__ A, int lda, int transA,
                       const float* __restrict__ x, const float* __restrict__ bias,
                       float* __restrict__ out, int M, int K)
{
  const int wave = threadIdx.x>>6, lane = threadIdx.x&63;
  const int row = blockIdx.x*4 + wave;
  if (row >= M) return;
  float s = 0.f;
  for (int k=lane; k<K; k+=64)
    s += (transA ? A[(size_t)k*lda + row] : A[(size_t)row*lda + k]) * x[k];
  s += __shfl_xor(s,32); s += __shfl_xor(s,16); s += __shfl_xor(s,8);
  s += __shfl_xor(s,4);  s += __shfl_xor(s,2);  s += __shfl_xor(s,1);
  if (lane==0) out[row] = s + (bias ? bias[row] : 0.f);
}

// ---------------- attention precompute: aggr[t] = softmax((v_t+e_t)@u) @ (v_t+e_t)
__global__ void attn_kernel(const float* __restrict__ V, const float* __restrict__ E,
                            const float* __restrict__ u, float* __restrict__ aggr)
{
  __shared__ float Es[NNBR][F_DIM+1];
  __shared__ float us[F_DIM];
  __shared__ float attn[NNBR];
  const int t = blockIdx.x, tid = threadIdx.x;
  if (tid < F_DIM) us[tid] = u[tid];
  const float* e = E + (size_t)t*NNBR*F_DIM;
  const float* v = V + (size_t)t*F_DIM;
  for (int idx=tid; idx<NNBR*F_DIM; idx+=256){
    int k = idx>>7, f = idx&127;
    Es[k][f] = e[idx] + v[f];
  }
  __syncthreads();
  if (tid < NNBR){
    float s = 0.f;
    #pragma unroll
    for (int f=0; f<F_DIM; f++) s += Es[tid][f]*us[f];
    float m = s;
    m = fmaxf(m, __shfl_xor(m,32)); m = fmaxf(m, __shfl_xor(m,16));
    m = fmaxf(m, __shfl_xor(m,8));  m = fmaxf(m, __shfl_xor(m,4));
    m = fmaxf(m, __shfl_xor(m,2));  m = fmaxf(m, __shfl_xor(m,1));
    float p = expf(s - m);
    float sum = p;
    sum += __shfl_xor(sum,32); sum += __shfl_xor(sum,16); sum += __shfl_xor(sum,8);
    sum += __shfl_xor(sum,4);  sum += __shfl_xor(sum,2);  sum += __shfl_xor(sum,1);
    attn[tid] = p / sum;
  }
  __syncthreads();
  if (tid < F_DIM){
    float a = 0.f;
    #pragma unroll
    for (int k=0; k<NNBR; k++) a += attn[k]*Es[k][tid];
    aggr[(size_t)t*F_DIM + tid] = a;
  }
}

// ---------------- persistent recurrent kernel: 64 wgs (32 F + 32 L) ----------------
// R7-proven protocol (per-thread tagged dependent polls, 16-lane teams, x4 replicated
// parallel publish) + split-wave polling: waves 0-1 poll the STALE vector while waves
// 2-3 poll the FRESH vector concurrently (4 words each), then ONE barrier, then all
// threads do both dots. Removes the serial stale-RTT and one barrier per phase.
__global__ __launch_bounds__(256, 1) void recurrent_kernel(
    const float* __restrict__ Hf,  const float* __restrict__ Whhf,
    const float* __restrict__ Hl,  const float* __restrict__ Whhl,
    const float* __restrict__ Mv,  const float* __restrict__ Ma,
    const float* __restrict__ V,   const float* __restrict__ aggr,
    const float* __restrict__ dfb, const float* __restrict__ dft,
    const float* __restrict__ dl,
    const float* __restrict__ bhhf,const float* __restrict__ bhhl,
    ull* __restrict__ h1rep, ull* __restrict__ h2rep,
    float* __restrict__ h2all)
{
  const int b = blockIdx.x;
  const bool isF = (b < GWGS);
  const int wgi = isF ? b : b - GWGS;
  const int tid = threadIdx.x;
  const int g   = wgi*256 + tid;
  const int j   = g >> 4;        // output element 0..511
  const int sub = g & 15;        // col-slice within 16-lane team
  const int cv0 = sub*8;
  const int rep = wgi & (NREP-1);

  __shared__ float sh1[2][16*LSTR];   // h1 vector staged per parity
  __shared__ float sh2[2][16*LSTR];   // h2 vector staged per parity

  // polling role: waves 0-1 -> stale vector, waves 2-3 -> fresh vector; 4 words each
  const bool stalePoller = (tid < 128);
  const int  pw0   = (tid & 127) * 4;               // first of this thread's 4 words
  const int  plofs = (pw0>>5)*LSTR + (pw0&31);      // LDS deposit base

  const float* WI = isF ? Hf   : Hl;
  const float* WH = isF ? Whhf : Whhl;
  const float* WM = isF ? Mv   : Ma;
  const float* xv_src = isF ? V : aggr;
  ull* __restrict__ own   = isF ? h1rep : h2rep;  // what this group publishes
  ull* __restrict__ fresh = isF ? h2rep : h1rep;  // critical input
  ull* __restrict__ stale = isF ? h1rep : h2rep;  // off-critical input

  float wI[3][32], wH[3][32], wM[3][8];
  #pragma unroll
  for (int r=0;r<3;r++){
    const int row = j + r*HID;
    const float4* qi = (const float4*)(WI + (size_t)row*HID + sub*32);
    const float4* qh = (const float4*)(WH + (size_t)row*HID + sub*32);
    #pragma unroll
    for (int i=0;i<8;i++){
      float4 a = qi[i]; wI[r][i*4+0]=a.x; wI[r][i*4+1]=a.y; wI[r][i*4+2]=a.z; wI[r][i*4+3]=a.w;
      float4 h = qh[i]; wH[r][i*4+0]=h.x; wH[r][i*4+1]=h.y; wH[r][i*4+2]=h.z; wH[r][i*4+3]=h.w;
    }
    const float4* qm = (const float4*)(WM + (size_t)row*F_DIM + cv0);
    #pragma unroll
    for (int i=0;i<2;i++){
      float4 m = qm[i]; wM[r][i*4+0]=m.x; wM[r][i*4+1]=m.y; wM[r][i*4+2]=m.z; wM[r][i*4+3]=m.w;
    }
  }
  // biases in ALL lanes (gates computed redundantly -> parallel replica publish)
  float bI0[3], bIT[3], bH[3];
  #pragma unroll
  for (int r=0;r<3;r++){
    const int row = j + r*HID;
    float base = isF ? dfb[row] : dl[row];
    bI0[r] = base;
    bIT[r] = base + (isF ? dft[row] : 0.f);
    bH[r]  = isF ? bhhf[row] : bhhl[row];
  }
  float hp = 0.f;

  for (int t=0; t<NSTEP; ++t){
    const int pw = t & 1, pr = pw ^ 1, par = t & 1;
    const unsigned tagc = (unsigned)t;      // tag of h produced at step t-1
    const unsigned tagp = (unsigned)(t+1);  // tag of h produced at step t
    const int fpar = isF ? pr : pw;         // F reads h2[t-1]; L reads h1[t]
    const unsigned ftag = isF ? tagc : tagp;
    const bool hasF = isF ? (t > 0) : true;
    const bool hasS = (t > 0);

    // independent stream input (cached)
    float xv[8];
    {
      const float4* q = (const float4*)(xv_src + (size_t)t*F_DIM + cv0);
      float4 a = q[0], bb = q[1];
      xv[0]=a.x; xv[1]=a.y; xv[2]=a.z; xv[3]=a.w;
      xv[4]=bb.x; xv[5]=bb.y; xv[6]=bb.z; xv[7]=bb.w;
    }
    float aI0=0,aI1=0,aI2=0,aH0=0,aH1=0,aH2=0;
    #pragma unroll
    for (int k=0;k<8;k++){
      float vv=xv[k];
      aI0 += wM[0][k]*vv; aI1 += wM[1][k]*vv; aI2 += wM[2][k]*vv;
    }

    // ---- parallel polls: waves 0-1 stale, waves 2-3 fresh; one barrier ----
    float* shS = isF ? &sh1[par][0] : &sh2[par][0];
    float* shF = isF ? &sh2[par][0] : &sh1[par][0];
    if (stalePoller){
      if (hasS)
        poll4(stale + ((size_t)pr*NREP + rep)*HID + pw0, tagc, &shS[plofs]);
    } else {
      if (hasF)
        poll4(fresh + ((size_t)fpar*NREP + rep)*HID + pw0, ftag, &shF[plofs]);
    }
    __syncthreads();

    // ---- both dots from LDS ----
    if (hasS){
      const float4* q = (const float4*)&shS[sub*LSTR];
      #pragma unroll
      for (int i=0;i<8;i++){
        float4 x = q[i];
        aH0 += wH[0][i*4+0]*x.x + wH[0][i*4+1]*x.y + wH[0][i*4+2]*x.z + wH[0][i*4+3]*x.w;
        aH1 += wH[1][i*4+0]*x.x + wH[1][i*4+1]*x.y + wH[1][i*4+2]*x.z + wH[1][i*4+3]*x.w;
        aH2 += wH[2][i*4+0]*x.x + wH[2][i*4+1]*x.y + wH[2][i*4+2]*x.z + wH[2][i*4+3]*x.w;
      }
    }
    if (hasF){
      const float4* q = (const float4*)&shF[sub*LSTR];
      #pragma unroll
      for (int i=0;i<8;i++){
        float4 x = q[i];
        aI0 += wI[0][i*4+0]*x.x + wI[0][i*4+1]*x.y + wI[0][i*4+2]*x.z + wI[0][i*4+3]*x.w;
        aI1 += wI[1][i*4+0]*x.x + wI[1][i*4+1]*x.y + wI[1][i*4+2]*x.z + wI[1][i*4+3]*x.w;
        aI2 += wI[2][i*4+0]*x.x + wI[2][i*4+1]*x.y + wI[2][i*4+2]*x.z + wI[2][i*4+3]*x.w;
      }
    }
    aH0 = red16(aH0); aH1 = red16(aH1); aH2 = red16(aH2);
    aI0 = red16(aI0); aI1 = red16(aI1); aI2 = red16(aI2);

    // gates in ALL lanes (red16 is an all-reduce) -> parallel replica publish
    {
      float gir = aI0 + (t>0 ? bIT[0] : bI0[0]);
      float giz = aI1 + (t>0 ? bIT[1] : bI0[1]);
      float gin = aI2 + (t>0 ? bIT[2] : bI0[2]);
      float r = sigmf(gir + aH0 + bH[0]);
      float z = sigmf(giz + aH1 + bH[1]);
      float n = tanhf(gin + r*(aH2 + bH[2]));
      float hn = (1.f - z)*n + z*hp;
      hp = hn;
      ull pk = ((ull)tagp << 32) | (ull)__float_as_uint(hn);
      if (sub < NREP)
        __hip_atomic_store(&own[((size_t)pw*NREP + sub)*HID + j], pk,
                           __ATOMIC_RELAXED, __HIP_MEMORY_SCOPE_AGENT);
      if (!isF && sub == 0)
        h2all[(size_t)t*HID + j] = hn;
    }
  }
}

extern "C" void kernel_launch(void* const* d_in, const int* in_sizes, int n_in,
                              void* d_out, int out_size, void* d_ws, size_t ws_size,
                              hipStream_t stream) {
  const float* V      = (const float*)d_in[0];
  const float* E      = (const float*)d_in[1];
  const float* W_e    = (const float*)d_in[2];
  const float* W_fc1  = (const float*)d_in[3];
  const float* b_fc1  = (const float*)d_in[4];
  const float* w_ih_f = (const float*)d_in[5];
  const float* w_hh_f = (const float*)d_in[6];
  const float* b_ih_f = (const float*)d_in[7];
  const float* b_hh_f = (const float*)d_in[8];
  const float* W_v    = (const float*)d_in[9];
  /* W_h (d_in[10]) cancels in softmax — unused */
  const float* W_a    = (const float*)d_in[11];
  const float* W_fc2  = (const float*)d_in[12];
  const float* b_fc2  = (const float*)d_in[13];
  const float* w_ih_l = (const float*)d_in[14];
  const float* w_hh_l = (const float*)d_in[15];
  const float* b_ih_l = (const float*)d_in[16];
  const float* b_hh_l = (const float*)d_in[17];
  const float* W_fc3  = (const float*)d_in[18];
  const float* b_fc3  = (const float*)d_in[19];
  float* out = (float*)d_out;

  float* W = (float*)d_ws;
  size_t o = 0;
  float* Hf   = W + o; o += (size_t)1536*512;
  float* Hl   = W + o; o += (size_t)1536*512;
  float* Mv   = W + o; o += (size_t)1536*128;
  float* Ma   = W + o; o += (size_t)1536*128;
  float* M1   = W + o; o += (size_t)512*300;
  float* G1   = W + o; o += (size_t)512*512;
  float* u    = W + o; o += 128;
  float* t1   = W + o; o += 512;
  float* dfb  = W + o; o += 1536;
  float* dft  = W + o; o += 1536;
  float* dl   = W + o; o += 1536;
  float* aggr = W + o; o += (size_t)NSTEP*128;
  float* h2all= W + o; o += (size_t)NSTEP*512;
  o = (o + 3) & ~(size_t)3;  // 16B align
  ull* h1rep = (ull*)(W + o); o += 2*(2*NREP*HID);   // u64[2][NREP][512]
  ull* h2rep = (ull*)(W + o); o += 2*(2*NREP*HID);
  (void)ws_size; (void)in_sizes; (void)n_in; (void)out_size;

  // reset tag buffers each launch (captured => every replay; kills ABA)
  hipMemsetAsync(h1rep, 0, 2ull*(2*NREP*HID)*sizeof(ull), stream);

  // u = W_v^T @ W_a[0]
  matvec<<<(128+3)/4, 256, 0, stream>>>(W_v, 128, 1, W_a, nullptr, u, 128, 128);
  // attention precompute (independent of recurrence)
  attn_kernel<<<NSTEP, 256, 0, stream>>>(V, E, u, aggr);
  // M1 = W_fc1[:,640:940] @ W_e                       [512x300]
  gemm_tiled<<<dim3(5,8), 256, 0, stream>>>(W_fc1+640, 940, W_e, 300, 0,
                                            nullptr, 0, nullptr, M1, 300, 512, 300, 300);
  // t1 = M1 @ b_fc3                                   [512]
  matvec<<<(512+3)/4, 256, 0, stream>>>(M1, 300, 0, b_fc3, nullptr, t1, 512, 300);
  // d_f_base = w_ih_f @ b_fc1 + b_ih_f                [1536]
  matvec<<<(1536+3)/4, 256, 0, stream>>>(w_ih_f, 512, 0, b_fc1, b_ih_f, dfb, 1536, 512);
  // d_f_tok = w_ih_f @ t1                             [1536]
  matvec<<<(1536+3)/4, 256, 0, stream>>>(w_ih_f, 512, 0, t1, nullptr, dft, 1536, 512);
  // d_l = w_ih_l @ b_fc2 + b_ih_l                     [1536]
  matvec<<<(1536+3)/4, 256, 0, stream>>>(w_ih_l, 512, 0, b_fc2, b_ih_l, dl, 1536, 512);
  // G1 = W_fc1[:,:512] + M1 @ W_fc3                   [512x512]
  gemm_tiled<<<dim3(8,8), 256, 0, stream>>>(M1, 300, W_fc3, 512, 0,
                                            W_fc1, 940, nullptr, G1, 512, 512, 512, 300);
  // Hf = w_ih_f @ G1                                  [1536x512]
  gemm_tiled<<<dim3(8,24), 256, 0, stream>>>(w_ih_f, 512, G1, 512, 0,
                                             nullptr, 0, nullptr, Hf, 512, 1536, 512, 512);
  // Hl = w_ih_l @ W_fc2[:,128:640]                    [1536x512]
  gemm_tiled<<<dim3(8,24), 256, 0, stream>>>(w_ih_l, 512, W_fc2+128, 640, 0,
                                             nullptr, 0, nullptr, Hl, 512, 1536, 512, 512);
  // Mv = w_ih_f @ W_fc1[:,512:640]                    [1536x128]
  gemm_tiled<<<dim3(2,24), 256, 0, stream>>>(w_ih_f, 512, W_fc1+512, 940, 0,
                                             nullptr, 0, nullptr, Mv, 128, 1536, 128, 512);
  // Ma = w_ih_l @ W_fc2[:,:128]                       [1536x128]
  gemm_tiled<<<dim3(2,24), 256, 0, stream>>>(w_ih_l, 512, W_fc2, 640, 0,
                                             nullptr, 0, nullptr, Ma, 128, 1536, 128, 512);
  // sequential recurrence: 64 persistent wgs (32 F + 32 L)
  recurrent_kernel<<<2*GWGS, 256, 0, stream>>>(Hf, w_hh_f, Hl, w_hh_l, Mv, Ma,
                                               V, aggr, dfb, dft, dl, b_hh_f, b_hh_l,
                                               h1rep, h2rep, h2all);
  // tokens = h2all @ W_fc3^T + b_fc3                  [4096x300]
  gemm_tiled<<<dim3(5,64), 256, 0, stream>>>(h2all, 512, W_fc3, 512, 1,
                                             nullptr, 0, b_fc3, out, 300, 4096, 300, 512);
}

// Round 11
// 15455.106 us; speedup vs baseline: 1.3387x; 1.3387x over previous
//
#include <hip/hip_runtime.h>
#include <math.h>

#define F_DIM 128
#define EMB 300
#define HID 512
#define NSTEP 4096
#define NNBR 64
#define GWGS 32   // workgroups per recurrent group (F and L)
#define NREP 8    // replication of published vectors (pollers per line: 32 -> 16)
#define LSTR 36   // LDS row stride (floats) — 16-lane teams => broadcast reads, 0 conflicts

typedef unsigned long long ull;

__device__ __forceinline__ float sigmf(float x){ return 1.0f/(1.0f + expf(-x)); }

__device__ __forceinline__ float red16(float v){
  v += __shfl_xor(v, 8);
  v += __shfl_xor(v, 4);
  v += __shfl_xor(v, 2);
  v += __shfl_xor(v, 1);
  return v;
}

__device__ __forceinline__ bool badtag(ull a, ull b, unsigned tag){
  return ((((unsigned)(a>>32)) ^ tag) | (((unsigned)(b>>32)) ^ tag)) != 0u;
}

// poll 2 consecutive packed {tag<<32|val} words until both tags match; deposit to LDS.
// Dependent tag-checked loop only — no early samples, no asm (R5/R9/R10 lessons).
__device__ __forceinline__ void poll2(const ull* __restrict__ p, unsigned tag,
                                      float* __restrict__ lds){
  ull a, b;
  for(;;){
    a = __hip_atomic_load(p,   __ATOMIC_RELAXED, __HIP_MEMORY_SCOPE_AGENT);
    b = __hip_atomic_load(p+1, __ATOMIC_RELAXED, __HIP_MEMORY_SCOPE_AGENT);
    if (!badtag(a, b, tag)) break;
  }
  *(float2*)lds = make_float2(__uint_as_float((unsigned)a), __uint_as_float((unsigned)b));
}

// ---------------- generic tiled f32 GEMM: C[M,N] = A[M,K]@B[K,N] (+D) (+bias_n) ----
__global__ void gemm_tiled(const float* __restrict__ A, int lda,
                           const float* __restrict__ B, int ldb, int transB,
                           const float* __restrict__ D, int ldd,
                           const float* __restrict__ bias,
                           float* __restrict__ C, int ldc,
                           int M, int N, int K)
{
  __shared__ float As[16][65];
  __shared__ float Bs[16][65];
  const int tid = threadIdx.x;
  const int m0 = blockIdx.y*64, n0 = blockIdx.x*64;
  const int ty = tid>>4, tx = tid&15;
  float acc[4][4] = {};
  for (int k0=0; k0<K; k0+=16){
    #pragma unroll
    for (int i=0;i<4;i++){
      int idx = tid + i*256;
      int m = idx>>4, k = idx&15;
      float va = 0.f;
      if (m0+m < M && k0+k < K) va = A[(size_t)(m0+m)*lda + k0+k];
      As[k][m] = va;
      int k2 = idx>>6, n = idx&63;
      float vb = 0.f;
      if (k0+k2 < K && n0+n < N)
        vb = transB ? B[(size_t)(n0+n)*ldb + k0+k2] : B[(size_t)(k0+k2)*ldb + n0+n];
      Bs[k2][n] = vb;
    }
    __syncthreads();
    #pragma unroll
    for (int k=0;k<16;k++){
      float a[4], b[4];
      #pragma unroll
      for (int i=0;i<4;i++) a[i] = As[k][ty*4+i];
      #pragma unroll
      for (int j=0;j<4;j++) b[j] = Bs[k][tx*4+j];
      #pragma unroll
      for (int i=0;i<4;i++)
        #pragma unroll
        for (int j=0;j<4;j++) acc[i][j] += a[i]*b[j];
    }
    __syncthreads();
  }
  #pragma unroll
  for (int i=0;i<4;i++){
    int m = m0 + ty*4 + i;
    if (m >= M) continue;
    #pragma unroll
    for (int j=0;j<4;j++){
      int n = n0 + tx*4 + j;
      if (n >= N) continue;
      float v = acc[i][j];
      if (D)    v += D[(size_t)m*ldd + n];
      if (bias) v += bias[n];
      C[(size_t)m*ldc + n] = v;
    }
  }
}

// ---------------- matvec: out[m] = sum_k A[m,k]*x[k] (+bias[m]); transA reads A[k,m]
__global__ void matvec(const float* __restrict__ A, int lda, int transA,
                       const float* __restrict__ x, const float* __restrict__ bias,
                       float* __restrict__ out, int M, int K)
{
  const int wave = threadIdx.x>>6, lane = threadIdx.x&63;
  const int row = blockIdx.x*4 + wave;
  if (row >= M) return;
  float s = 0.f;
  for (int k=lane; k<K; k+=64)
    s += (transA ? A[(size_t)k*lda + row] : A[(size_t)row*lda + k]) * x[k];
  s += __shfl_xor(s,32); s += __shfl_xor(s,16); s += __shfl_xor(s,8);
  s += __shfl_xor(s,4);  s += __shfl_xor(s,2);  s += __shfl_xor(s,1);
  if (lane==0) out[row] = s + (bias ? bias[row] : 0.f);
}

// ---------------- attention precompute: aggr[t] = softmax((v_t+e_t)@u) @ (v_t+e_t)
__global__ void attn_kernel(const float* __restrict__ V, const float* __restrict__ E,
                            const float* __restrict__ u, float* __restrict__ aggr)
{
  __shared__ float Es[NNBR][F_DIM+1];
  __shared__ float us[F_DIM];
  __shared__ float attn[NNBR];
  const int t = blockIdx.x, tid = threadIdx.x;
  if (tid < F_DIM) us[tid] = u[tid];
  const float* e = E + (size_t)t*NNBR*F_DIM;
  const float* v = V + (size_t)t*F_DIM;
  for (int idx=tid; idx<NNBR*F_DIM; idx+=256){
    int k = idx>>7, f = idx&127;
    Es[k][f] = e[idx] + v[f];
  }
  __syncthreads();
  if (tid < NNBR){
    float s = 0.f;
    #pragma unroll
    for (int f=0; f<F_DIM; f++) s += Es[tid][f]*us[f];
    float m = s;
    m = fmaxf(m, __shfl_xor(m,32)); m = fmaxf(m, __shfl_xor(m,16));
    m = fmaxf(m, __shfl_xor(m,8));  m = fmaxf(m, __shfl_xor(m,4));
    m = fmaxf(m, __shfl_xor(m,2));  m = fmaxf(m, __shfl_xor(m,1));
    float p = expf(s - m);
    float sum = p;
    sum += __shfl_xor(sum,32); sum += __shfl_xor(sum,16); sum += __shfl_xor(sum,8);
    sum += __shfl_xor(sum,4);  sum += __shfl_xor(sum,2);  sum += __shfl_xor(sum,1);
    attn[tid] = p / sum;
  }
  __syncthreads();
  if (tid < F_DIM){
    float a = 0.f;
    #pragma unroll
    for (int k=0; k<NNBR; k++) a += attn[k]*Es[k][tid];
    aggr[(size_t)t*F_DIM + tid] = a;
  }
}

// ---------------- persistent recurrent kernel: 64 wgs (32 F + 32 L) ----------------
// R7-proven skeleton: per-thread 2-word tagged dependent polls, 16-lane teams
// (broadcast LDS reads, 0 conflicts), stale poll late (protects the publish window),
// x-replicated publish written in parallel by lanes sub<NREP.
// R11 single change: NREP 4 -> 8 (pollers per replica line halved).
__global__ __launch_bounds__(256, 1) void recurrent_kernel(
    const float* __restrict__ Hf,  const float* __restrict__ Whhf,
    const float* __restrict__ Hl,  const float* __restrict__ Whhl,
    const float* __restrict__ Mv,  const float* __restrict__ Ma,
    const float* __restrict__ V,   const float* __restrict__ aggr,
    const float* __restrict__ dfb, const float* __restrict__ dft,
    const float* __restrict__ dl,
    const float* __restrict__ bhhf,const float* __restrict__ bhhl,
    ull* __restrict__ h1rep, ull* __restrict__ h2rep,
    float* __restrict__ h2all)
{
  const int b = blockIdx.x;
  const bool isF = (b < GWGS);
  const int wgi = isF ? b : b - GWGS;
  const int tid = threadIdx.x;
  const int g   = wgi*256 + tid;
  const int j   = g >> 4;        // output element 0..511
  const int sub = g & 15;        // col-slice within 16-lane team
  const int cv0 = sub*8;
  const int rep = wgi & (NREP-1);

  __shared__ float sh1[2][16*LSTR];   // h1 vector staged per parity
  __shared__ float sh2[2][16*LSTR];   // h2 vector staged per parity

  const int w0   = tid*2;                   // this thread's 2 poll words
  const int lofs = (w0>>5)*LSTR + (w0&31);  // LDS deposit offset

  const float* WI = isF ? Hf   : Hl;
  const float* WH = isF ? Whhf : Whhl;
  const float* WM = isF ? Mv   : Ma;
  const float* xv_src = isF ? V : aggr;
  ull* __restrict__ own   = isF ? h1rep : h2rep;  // what this group publishes
  ull* __restrict__ fresh = isF ? h2rep : h1rep;  // critical input
  ull* __restrict__ stale = isF ? h1rep : h2rep;  // off-critical input

  float wI[3][32], wH[3][32], wM[3][8];
  #pragma unroll
  for (int r=0;r<3;r++){
    const int row = j + r*HID;
    const float4* qi = (const float4*)(WI + (size_t)row*HID + sub*32);
    const float4* qh = (const float4*)(WH + (size_t)row*HID + sub*32);
    #pragma unroll
    for (int i=0;i<8;i++){
      float4 a = qi[i]; wI[r][i*4+0]=a.x; wI[r][i*4+1]=a.y; wI[r][i*4+2]=a.z; wI[r][i*4+3]=a.w;
      float4 h = qh[i]; wH[r][i*4+0]=h.x; wH[r][i*4+1]=h.y; wH[r][i*4+2]=h.z; wH[r][i*4+3]=h.w;
    }
    const float4* qm = (const float4*)(WM + (size_t)row*F_DIM + cv0);
    #pragma unroll
    for (int i=0;i<2;i++){
      float4 m = qm[i]; wM[r][i*4+0]=m.x; wM[r][i*4+1]=m.y; wM[r][i*4+2]=m.z; wM[r][i*4+3]=m.w;
    }
  }
  // biases in ALL lanes (gates computed redundantly -> parallel replica publish)
  float bI0[3], bIT[3], bH[3];
  #pragma unroll
  for (int r=0;r<3;r++){
    const int row = j + r*HID;
    float base = isF ? dfb[row] : dl[row];
    bI0[r] = base;
    bIT[r] = base + (isF ? dft[row] : 0.f);
    bH[r]  = isF ? bhhf[row] : bhhl[row];
  }
  float hp = 0.f;

  for (int t=0; t<NSTEP; ++t){
    const int pw = t & 1, pr = pw ^ 1, par = t & 1;
    const unsigned tagc = (unsigned)t;      // tag of h produced at step t-1
    const unsigned tagp = (unsigned)(t+1);  // tag of h produced at step t

    // independent stream input (cached)
    float xv[8];
    {
      const float4* q = (const float4*)(xv_src + (size_t)t*F_DIM + cv0);
      float4 a = q[0], bb = q[1];
      xv[0]=a.x; xv[1]=a.y; xv[2]=a.z; xv[3]=a.w;
      xv[4]=bb.x; xv[5]=bb.y; xv[6]=bb.z; xv[7]=bb.w;
    }
    float aI0=0,aI1=0,aI2=0,aH0=0,aH1=0,aH2=0;
    #pragma unroll
    for (int k=0;k<8;k++){
      float vv=xv[k];
      aI0 += wM[0][k]*vv; aI1 += wM[1][k]*vv; aI2 += wM[2][k]*vv;
    }

    // ---- phase A: stale own-state (published one phase ago — near-instant) ----
    float* shS = isF ? &sh1[par][0] : &sh2[par][0];
    if (t > 0){
      poll2(stale + ((size_t)pr*NREP + rep)*HID + w0, tagc, &shS[lofs]);
    }
    __syncthreads();
    if (t > 0){
      const float4* q = (const float4*)&shS[sub*LSTR];
      #pragma unroll
      for (int i=0;i<8;i++){
        float4 x = q[i];
        aH0 += wH[0][i*4+0]*x.x + wH[0][i*4+1]*x.y + wH[0][i*4+2]*x.z + wH[0][i*4+3]*x.w;
        aH1 += wH[1][i*4+0]*x.x + wH[1][i*4+1]*x.y + wH[1][i*4+2]*x.z + wH[1][i*4+3]*x.w;
        aH2 += wH[2][i*4+0]*x.x + wH[2][i*4+1]*x.y + wH[2][i*4+2]*x.z + wH[2][i*4+3]*x.w;
      }
    }
    aH0 = red16(aH0); aH1 = red16(aH1); aH2 = red16(aH2);

    // ---- phase B: fresh other-state (the critical input) ----
    float* shF = isF ? &sh2[par][0] : &sh1[par][0];
    const int fpar = isF ? pr : pw;             // F reads h2[t-1]; L reads h1[t]
    const unsigned ftag = isF ? tagc : tagp;
    if (isF ? (t > 0) : true){
      poll2(fresh + ((size_t)fpar*NREP + rep)*HID + w0, ftag, &shF[lofs]);
    }
    __syncthreads();
    if (isF ? (t > 0) : true){
      const float4* q = (const float4*)&shF[sub*LSTR];
      #pragma unroll
      for (int i=0;i<8;i++){
        float4 x = q[i];
        aI0 += wI[0][i*4+0]*x.x + wI[0][i*4+1]*x.y + wI[0][i*4+2]*x.z + wI[0][i*4+3]*x.w;
        aI1 += wI[1][i*4+0]*x.x + wI[1][i*4+1]*x.y + wI[1][i*4+2]*x.z + wI[1][i*4+3]*x.w;
        aI2 += wI[2][i*4+0]*x.x + wI[2][i*4+1]*x.y + wI[2][i*4+2]*x.z + wI[2][i*4+3]*x.w;
      }
    }
    aI0 = red16(aI0); aI1 = red16(aI1); aI2 = red16(aI2);

    // gates in ALL lanes (red16 is an all-reduce) -> parallel replica publish
    {
      float gir = aI0 + (t>0 ? bIT[0] : bI0[0]);
      float giz = aI1 + (t>0 ? bIT[1] : bI0[1]);
      float gin = aI2 + (t>0 ? bIT[2] : bI0[2]);
      float r = sigmf(gir + aH0 + bH[0]);
      float z = sigmf(giz + aH1 + bH[1]);
      float n = tanhf(gin + r*(aH2 + bH[2]));
      float hn = (1.f - z)*n + z*hp;
      hp = hn;
      ull pk = ((ull)tagp << 32) | (ull)__float_as_uint(hn);
      if (sub < NREP)
        __hip_atomic_store(&own[((size_t)pw*NREP + sub)*HID + j], pk,
                           __ATOMIC_RELAXED, __HIP_MEMORY_SCOPE_AGENT);
      if (!isF && sub == 0)
        h2all[(size_t)t*HID + j] = hn;
    }
  }
}

extern "C" void kernel_launch(void* const* d_in, const int* in_sizes, int n_in,
                              void* d_out, int out_size, void* d_ws, size_t ws_size,
                              hipStream_t stream) {
  const float* V      = (const float*)d_in[0];
  const float* E      = (const float*)d_in[1];
  const float* W_e    = (const float*)d_in[2];
  const float* W_fc1  = (const float*)d_in[3];
  const float* b_fc1  = (const float*)d_in[4];
  const float* w_ih_f = (const float*)d_in[5];
  const float* w_hh_f = (const float*)d_in[6];
  const float* b_ih_f = (const float*)d_in[7];
  const float* b_hh_f = (const float*)d_in[8];
  const float* W_v    = (const float*)d_in[9];
  /* W_h (d_in[10]) cancels in softmax — unused */
  const float* W_a    = (const float*)d_in[11];
  const float* W_fc2  = (const float*)d_in[12];
  const float* b_fc2  = (const float*)d_in[13];
  const float* w_ih_l = (const float*)d_in[14];
  const float* w_hh_l = (const float*)d_in[15];
  const float* b_ih_l = (const float*)d_in[16];
  const float* b_hh_l = (const float*)d_in[17];
  const float* W_fc3  = (const float*)d_in[18];
  const float* b_fc3  = (const float*)d_in[19];
  float* out = (float*)d_out;

  float* W = (float*)d_ws;
  size_t o = 0;
  float* Hf   = W + o; o += (size_t)1536*512;
  float* Hl   = W + o; o += (size_t)1536*512;
  float* Mv   = W + o; o += (size_t)1536*128;
  float* Ma   = W + o; o += (size_t)1536*128;
  float* M1   = W + o; o += (size_t)512*300;
  float* G1   = W + o; o += (size_t)512*512;
  float* u    = W + o; o += 128;
  float* t1   = W + o; o += 512;
  float* dfb  = W + o; o += 1536;
  float* dft  = W + o; o += 1536;
  float* dl   = W + o; o += 1536;
  float* aggr = W + o; o += (size_t)NSTEP*128;
  float* h2all= W + o; o += (size_t)NSTEP*512;
  o = (o + 3) & ~(size_t)3;  // 16B align
  ull* h1rep = (ull*)(W + o); o += 2*(2*NREP*HID);   // u64[2][NREP][512]
  ull* h2rep = (ull*)(W + o); o += 2*(2*NREP*HID);
  (void)ws_size; (void)in_sizes; (void)n_in; (void)out_size;

  // reset tag buffers each launch (captured => every replay; kills ABA)
  hipMemsetAsync(h1rep, 0, 2ull*(2*NREP*HID)*sizeof(ull), stream);

  // u = W_v^T @ W_a[0]
  matvec<<<(128+3)/4, 256, 0, stream>>>(W_v, 128, 1, W_a, nullptr, u, 128, 128);
  // attention precompute (independent of recurrence)
  attn_kernel<<<NSTEP, 256, 0, stream>>>(V, E, u, aggr);
  // M1 = W_fc1[:,640:940] @ W_e                       [512x300]
  gemm_tiled<<<dim3(5,8), 256, 0, stream>>>(W_fc1+640, 940, W_e, 300, 0,
                                            nullptr, 0, nullptr, M1, 300, 512, 300, 300);
  // t1 = M1 @ b_fc3                                   [512]
  matvec<<<(512+3)/4, 256, 0, stream>>>(M1, 300, 0, b_fc3, nullptr, t1, 512, 300);
  // d_f_base = w_ih_f @ b_fc1 + b_ih_f                [1536]
  matvec<<<(1536+3)/4, 256, 0, stream>>>(w_ih_f, 512, 0, b_fc1, b_ih_f, dfb, 1536, 512);
  // d_f_tok = w_ih_f @ t1                             [1536]
  matvec<<<(1536+3)/4, 256, 0, stream>>>(w_ih_f, 512, 0, t1, nullptr, dft, 1536, 512);
  // d_l = w_ih_l @ b_fc2 + b_ih_l                     [1536]
  matvec<<<(1536+3)/4, 256, 0, stream>>>(w_ih_l, 512, 0, b_fc2, b_ih_l, dl, 1536, 512);
  // G1 = W_fc1[:,:512] + M1 @ W_fc3                   [512x512]
  gemm_tiled<<<dim3(8,8), 256, 0, stream>>>(M1, 300, W_fc3, 512, 0,
                                            W_fc1, 940, nullptr, G1, 512, 512, 512, 300);
  // Hf = w_ih_f @ G1                                  [1536x512]
  gemm_tiled<<<dim3(8,24), 256, 0, stream>>>(w_ih_f, 512, G1, 512, 0,
                                             nullptr, 0, nullptr, Hf, 512, 1536, 512, 512);
  // Hl = w_ih_l @ W_fc2[:,128:640]                    [1536x512]
  gemm_tiled<<<dim3(8,24), 256, 0, stream>>>(w_ih_l, 512, W_fc2+128, 640, 0,
                                             nullptr, 0, nullptr, Hl, 512, 1536, 512, 512);
  // Mv = w_ih_f @ W_fc1[:,512:640]                    [1536x128]
  gemm_tiled<<<dim3(2,24), 256, 0, stream>>>(w_ih_f, 512, W_fc1+512, 940, 0,
                                             nullptr, 0, nullptr, Mv, 128, 1536, 128, 512);
  // Ma = w_ih_l @ W_fc2[:,:128]                       [1536x128]
  gemm_tiled<<<dim3(2,24), 256, 0, stream>>>(w_ih_l, 512, W_fc2, 640, 0,
                                             nullptr, 0, nullptr, Ma, 128, 1536, 128, 512);
  // sequential recurrence: 64 persistent wgs (32 F + 32 L)
  recurrent_kernel<<<2*GWGS, 256, 0, stream>>>(Hf, w_hh_f, Hl, w_hh_l, Mv, Ma,
                                               V, aggr, dfb, dft, dl, b_hh_f, b_hh_l,
                                               h1rep, h2rep, h2all);
  // tokens = h2all @ W_fc3^T + b_fc3                  [4096x300]
  gemm_tiled<<<dim3(5,64), 256, 0, stream>>>(h2all, 512, W_fc3, 512, 1,
                                             nullptr, 0, b_fc3, out, 300, 4096, 300, 512);
}

// Round 12
// 14725.693 us; speedup vs baseline: 1.4050x; 1.0495x over previous
//
#include <hip/hip_runtime.h>
#include <math.h>

#define F_DIM 128
#define EMB 300
#define HID 512
#define NSTEP 4096
#define NNBR 64
#define GWGS 32   // workgroups per recurrent group (F and L)
#define NREP 8    // replication of published vectors
#define LSTR 36   // LDS row stride (floats) — 16-lane teams => broadcast reads, 0 conflicts

typedef unsigned long long ull;

__device__ __forceinline__ float sigmf(float x){ return 1.0f/(1.0f + expf(-x)); }

__device__ __forceinline__ float red16(float v){
  v += __shfl_xor(v, 8);
  v += __shfl_xor(v, 4);
  v += __shfl_xor(v, 2);
  v += __shfl_xor(v, 1);
  return v;
}

__device__ __forceinline__ bool badtag(ull a, ull b, unsigned tag){
  return ((((unsigned)(a>>32)) ^ tag) | (((unsigned)(b>>32)) ^ tag)) != 0u;
}

// poll 2 consecutive packed {tag<<32|val} words until both tags match; deposit to LDS.
// Dependent tag-checked loop only — no early samples, no asm loads (R5/R9/R10 lessons).
__device__ __forceinline__ void poll2(const ull* __restrict__ p, unsigned tag,
                                      float* __restrict__ lds){
  ull a, b;
  for(;;){
    a = __hip_atomic_load(p,   __ATOMIC_RELAXED, __HIP_MEMORY_SCOPE_AGENT);
    b = __hip_atomic_load(p+1, __ATOMIC_RELAXED, __HIP_MEMORY_SCOPE_AGENT);
    if (!badtag(a, b, tag)) break;
  }
  *(float2*)lds = make_float2(__uint_as_float((unsigned)a), __uint_as_float((unsigned)b));
}

// ---------------- generic tiled f32 GEMM: C[M,N] = A[M,K]@B[K,N] (+D) (+bias_n) ----
__global__ void gemm_tiled(const float* __restrict__ A, int lda,
                           const float* __restrict__ B, int ldb, int transB,
                           const float* __restrict__ D, int ldd,
                           const float* __restrict__ bias,
                           float* __restrict__ C, int ldc,
                           int M, int N, int K)
{
  __shared__ float As[16][65];
  __shared__ float Bs[16][65];
  const int tid = threadIdx.x;
  const int m0 = blockIdx.y*64, n0 = blockIdx.x*64;
  const int ty = tid>>4, tx = tid&15;
  float acc[4][4] = {};
  for (int k0=0; k0<K; k0+=16){
    #pragma unroll
    for (int i=0;i<4;i++){
      int idx = tid + i*256;
      int m = idx>>4, k = idx&15;
      float va = 0.f;
      if (m0+m < M && k0+k < K) va = A[(size_t)(m0+m)*lda + k0+k];
      As[k][m] = va;
      int k2 = idx>>6, n = idx&63;
      float vb = 0.f;
      if (k0+k2 < K && n0+n < N)
        vb = transB ? B[(size_t)(n0+n)*ldb + k0+k2] : B[(size_t)(k0+k2)*ldb + n0+n];
      Bs[k2][n] = vb;
    }
    __syncthreads();
    #pragma unroll
    for (int k=0;k<16;k++){
      float a[4], b[4];
      #pragma unroll
      for (int i=0;i<4;i++) a[i] = As[k][ty*4+i];
      #pragma unroll
      for (int j=0;j<4;j++) b[j] = Bs[k][tx*4+j];
      #pragma unroll
      for (int i=0;i<4;i++)
        #pragma unroll
        for (int j=0;j<4;j++) acc[i][j] += a[i]*b[j];
    }
    __syncthreads();
  }
  #pragma unroll
  for (int i=0;i<4;i++){
    int m = m0 + ty*4 + i;
    if (m >= M) continue;
    #pragma unroll
    for (int j=0;j<4;j++){
      int n = n0 + tx*4 + j;
      if (n >= N) continue;
      float v = acc[i][j];
      if (D)    v += D[(size_t)m*ldd + n];
      if (bias) v += bias[n];
      C[(size_t)m*ldc + n] = v;
    }
  }
}

// ---------------- matvec: out[m] = sum_k A[m,k]*x[k] (+bias[m]); transA reads A[k,m]
__global__ void matvec(const float* __restrict__ A, int lda, int transA,
                       const float* __restrict__ x, const float* __restrict__ bias,
                       float* __restrict__ out, int M, int K)
{
  const int wave = threadIdx.x>>6, lane = threadIdx.x&63;
  const int row = blockIdx.x*4 + wave;
  if (row >= M) return;
  float s = 0.f;
  for (int k=lane; k<K; k+=64)
    s += (transA ? A[(size_t)k*lda + row] : A[(size_t)row*lda + k]) * x[k];
  s += __shfl_xor(s,32); s += __shfl_xor(s,16); s += __shfl_xor(s,8);
  s += __shfl_xor(s,4);  s += __shfl_xor(s,2);  s += __shfl_xor(s,1);
  if (lane==0) out[row] = s + (bias ? bias[row] : 0.f);
}

// ---------------- attention precompute: aggr[t] = softmax((v_t+e_t)@u) @ (v_t+e_t)
__global__ void attn_kernel(const float* __restrict__ V, const float* __restrict__ E,
                            const float* __restrict__ u, float* __restrict__ aggr)
{
  __shared__ float Es[NNBR][F_DIM+1];
  __shared__ float us[F_DIM];
  __shared__ float attn[NNBR];
  const int t = blockIdx.x, tid = threadIdx.x;
  if (tid < F_DIM) us[tid] = u[tid];
  const float* e = E + (size_t)t*NNBR*F_DIM;
  const float* v = V + (size_t)t*F_DIM;
  for (int idx=tid; idx<NNBR*F_DIM; idx+=256){
    int k = idx>>7, f = idx&127;
    Es[k][f] = e[idx] + v[f];
  }
  __syncthreads();
  if (tid < NNBR){
    float s = 0.f;
    #pragma unroll
    for (int f=0; f<F_DIM; f++) s += Es[tid][f]*us[f];
    float m = s;
    m = fmaxf(m, __shfl_xor(m,32)); m = fmaxf(m, __shfl_xor(m,16));
    m = fmaxf(m, __shfl_xor(m,8));  m = fmaxf(m, __shfl_xor(m,4));
    m = fmaxf(m, __shfl_xor(m,2));  m = fmaxf(m, __shfl_xor(m,1));
    float p = expf(s - m);
    float sum = p;
    sum += __shfl_xor(sum,32); sum += __shfl_xor(sum,16); sum += __shfl_xor(sum,8);
    sum += __shfl_xor(sum,4);  sum += __shfl_xor(sum,2);  sum += __shfl_xor(sum,1);
    attn[tid] = p / sum;
  }
  __syncthreads();
  if (tid < F_DIM){
    float a = 0.f;
    #pragma unroll
    for (int k=0; k<NNBR; k++) a += attn[k]*Es[k][tid];
    aggr[(size_t)t*F_DIM + tid] = a;
  }
}

// ---------------- persistent recurrent kernel: 64 wgs (32 F + 32 L) ----------------
// R7/R11-proven skeleton: per-thread 2-word tagged dependent polls, 16-lane teams
// (broadcast LDS reads, 0 conflicts), stale poll late, x8-replicated parallel publish.
// R12 single change: s_waitcnt vmcnt(0) after the publish stores — forces the replica
// stores to complete at the coherence point before this wave issues next-phase poll
// reads (kills lazy-drain / self-interference on the publish path).
__global__ __launch_bounds__(256, 1) void recurrent_kernel(
    const float* __restrict__ Hf,  const float* __restrict__ Whhf,
    const float* __restrict__ Hl,  const float* __restrict__ Whhl,
    const float* __restrict__ Mv,  const float* __restrict__ Ma,
    const float* __restrict__ V,   const float* __restrict__ aggr,
    const float* __restrict__ dfb, const float* __restrict__ dft,
    const float* __restrict__ dl,
    const float* __restrict__ bhhf,const float* __restrict__ bhhl,
    ull* __restrict__ h1rep, ull* __restrict__ h2rep,
    float* __restrict__ h2all)
{
  const int b = blockIdx.x;
  const bool isF = (b < GWGS);
  const int wgi = isF ? b : b - GWGS;
  const int tid = threadIdx.x;
  const int g   = wgi*256 + tid;
  const int j   = g >> 4;        // output element 0..511
  const int sub = g & 15;        // col-slice within 16-lane team
  const int cv0 = sub*8;
  const int rep = wgi & (NREP-1);

  __shared__ float sh1[2][16*LSTR];   // h1 vector staged per parity
  __shared__ float sh2[2][16*LSTR];   // h2 vector staged per parity

  const int w0   = tid*2;                   // this thread's 2 poll words
  const int lofs = (w0>>5)*LSTR + (w0&31);  // LDS deposit offset

  const float* WI = isF ? Hf   : Hl;
  const float* WH = isF ? Whhf : Whhl;
  const float* WM = isF ? Mv   : Ma;
  const float* xv_src = isF ? V : aggr;
  ull* __restrict__ own   = isF ? h1rep : h2rep;  // what this group publishes
  ull* __restrict__ fresh = isF ? h2rep : h1rep;  // critical input
  ull* __restrict__ stale = isF ? h1rep : h2rep;  // off-critical input

  float wI[3][32], wH[3][32], wM[3][8];
  #pragma unroll
  for (int r=0;r<3;r++){
    const int row = j + r*HID;
    const float4* qi = (const float4*)(WI + (size_t)row*HID + sub*32);
    const float4* qh = (const float4*)(WH + (size_t)row*HID + sub*32);
    #pragma unroll
    for (int i=0;i<8;i++){
      float4 a = qi[i]; wI[r][i*4+0]=a.x; wI[r][i*4+1]=a.y; wI[r][i*4+2]=a.z; wI[r][i*4+3]=a.w;
      float4 h = qh[i]; wH[r][i*4+0]=h.x; wH[r][i*4+1]=h.y; wH[r][i*4+2]=h.z; wH[r][i*4+3]=h.w;
    }
    const float4* qm = (const float4*)(WM + (size_t)row*F_DIM + cv0);
    #pragma unroll
    for (int i=0;i<2;i++){
      float4 m = qm[i]; wM[r][i*4+0]=m.x; wM[r][i*4+1]=m.y; wM[r][i*4+2]=m.z; wM[r][i*4+3]=m.w;
    }
  }
  // biases in ALL lanes (gates computed redundantly -> parallel replica publish)
  float bI0[3], bIT[3], bH[3];
  #pragma unroll
  for (int r=0;r<3;r++){
    const int row = j + r*HID;
    float base = isF ? dfb[row] : dl[row];
    bI0[r] = base;
    bIT[r] = base + (isF ? dft[row] : 0.f);
    bH[r]  = isF ? bhhf[row] : bhhl[row];
  }
  float hp = 0.f;

  for (int t=0; t<NSTEP; ++t){
    const int pw = t & 1, pr = pw ^ 1, par = t & 1;
    const unsigned tagc = (unsigned)t;      // tag of h produced at step t-1
    const unsigned tagp = (unsigned)(t+1);  // tag of h produced at step t

    // independent stream input (cached)
    float xv[8];
    {
      const float4* q = (const float4*)(xv_src + (size_t)t*F_DIM + cv0);
      float4 a = q[0], bb = q[1];
      xv[0]=a.x; xv[1]=a.y; xv[2]=a.z; xv[3]=a.w;
      xv[4]=bb.x; xv[5]=bb.y; xv[6]=bb.z; xv[7]=bb.w;
    }
    float aI0=0,aI1=0,aI2=0,aH0=0,aH1=0,aH2=0;
    #pragma unroll
    for (int k=0;k<8;k++){
      float vv=xv[k];
      aI0 += wM[0][k]*vv; aI1 += wM[1][k]*vv; aI2 += wM[2][k]*vv;
    }

    // ---- phase A: own-group state from the previous phase ----
    float* shS = isF ? &sh1[par][0] : &sh2[par][0];
    if (t > 0){
      poll2(stale + ((size_t)pr*NREP + rep)*HID + w0, tagc, &shS[lofs]);
    }
    __syncthreads();
    if (t > 0){
      const float4* q = (const float4*)&shS[sub*LSTR];
      #pragma unroll
      for (int i=0;i<8;i++){
        float4 x = q[i];
        aH0 += wH[0][i*4+0]*x.x + wH[0][i*4+1]*x.y + wH[0][i*4+2]*x.z + wH[0][i*4+3]*x.w;
        aH1 += wH[1][i*4+0]*x.x + wH[1][i*4+1]*x.y + wH[1][i*4+2]*x.z + wH[1][i*4+3]*x.w;
        aH2 += wH[2][i*4+0]*x.x + wH[2][i*4+1]*x.y + wH[2][i*4+2]*x.z + wH[2][i*4+3]*x.w;
      }
    }
    aH0 = red16(aH0); aH1 = red16(aH1); aH2 = red16(aH2);

    // ---- phase B: fresh other-group state (the critical input) ----
    float* shF = isF ? &sh2[par][0] : &sh1[par][0];
    const int fpar = isF ? pr : pw;             // F reads h2[t-1]; L reads h1[t]
    const unsigned ftag = isF ? tagc : tagp;
    if (isF ? (t > 0) : true){
      poll2(fresh + ((size_t)fpar*NREP + rep)*HID + w0, ftag, &shF[lofs]);
    }
    __syncthreads();
    if (isF ? (t > 0) : true){
      const float4* q = (const float4*)&shF[sub*LSTR];
      #pragma unroll
      for (int i=0;i<8;i++){
        float4 x = q[i];
        aI0 += wI[0][i*4+0]*x.x + wI[0][i*4+1]*x.y + wI[0][i*4+2]*x.z + wI[0][i*4+3]*x.w;
        aI1 += wI[1][i*4+0]*x.x + wI[1][i*4+1]*x.y + wI[1][i*4+2]*x.z + wI[1][i*4+3]*x.w;
        aI2 += wI[2][i*4+0]*x.x + wI[2][i*4+1]*x.y + wI[2][i*4+2]*x.z + wI[2][i*4+3]*x.w;
      }
    }
    aI0 = red16(aI0); aI1 = red16(aI1); aI2 = red16(aI2);

    // gates in ALL lanes (red16 is an all-reduce) -> parallel replica publish
    {
      float gir = aI0 + (t>0 ? bIT[0] : bI0[0]);
      float giz = aI1 + (t>0 ? bIT[1] : bI0[1]);
      float gin = aI2 + (t>0 ? bIT[2] : bI0[2]);
      float r = sigmf(gir + aH0 + bH[0]);
      float z = sigmf(giz + aH1 + bH[1]);
      float n = tanhf(gin + r*(aH2 + bH[2]));
      float hn = (1.f - z)*n + z*hp;
      hp = hn;
      ull pk = ((ull)tagp << 32) | (ull)__float_as_uint(hn);
      if (sub < NREP)
        __hip_atomic_store(&own[((size_t)pw*NREP + sub)*HID + j], pk,
                           __ATOMIC_RELAXED, __HIP_MEMORY_SCOPE_AGENT);
      if (!isF && sub == 0)
        h2all[(size_t)t*HID + j] = hn;
    }
    // R12: drain the publish stores to the coherence point before issuing any
    // next-phase poll reads. imm 0x0f70 = vmcnt(0), lgkmcnt/expcnt unconstrained.
    __builtin_amdgcn_s_waitcnt(0x0f70);
  }
}

extern "C" void kernel_launch(void* const* d_in, const int* in_sizes, int n_in,
                              void* d_out, int out_size, void* d_ws, size_t ws_size,
                              hipStream_t stream) {
  const float* V      = (const float*)d_in[0];
  const float* E      = (const float*)d_in[1];
  const float* W_e    = (const float*)d_in[2];
  const float* W_fc1  = (const float*)d_in[3];
  const float* b_fc1  = (const float*)d_in[4];
  const float* w_ih_f = (const float*)d_in[5];
  const float* w_hh_f = (const float*)d_in[6];
  const float* b_ih_f = (const float*)d_in[7];
  const float* b_hh_f = (const float*)d_in[8];
  const float* W_v    = (const float*)d_in[9];
  /* W_h (d_in[10]) cancels in softmax — unused */
  const float* W_a    = (const float*)d_in[11];
  const float* W_fc2  = (const float*)d_in[12];
  const float* b_fc2  = (const float*)d_in[13];
  const float* w_ih_l = (const float*)d_in[14];
  const float* w_hh_l = (const float*)d_in[15];
  const float* b_ih_l = (const float*)d_in[16];
  const float* b_hh_l = (const float*)d_in[17];
  const float* W_fc3  = (const float*)d_in[18];
  const float* b_fc3  = (const float*)d_in[19];
  float* out = (float*)d_out;

  float* W = (float*)d_ws;
  size_t o = 0;
  float* Hf   = W + o; o += (size_t)1536*512;
  float* Hl   = W + o; o += (size_t)1536*512;
  float* Mv   = W + o; o += (size_t)1536*128;
  float* Ma   = W + o; o += (size_t)1536*128;
  float* M1   = W + o; o += (size_t)512*300;
  float* G1   = W + o; o += (size_t)512*512;
  float* u    = W + o; o += 128;
  float* t1   = W + o; o += 512;
  float* dfb  = W + o; o += 1536;
  float* dft  = W + o; o += 1536;
  float* dl   = W + o; o += 1536;
  float* aggr = W + o; o += (size_t)NSTEP*128;
  float* h2all= W + o; o += (size_t)NSTEP*512;
  o = (o + 3) & ~(size_t)3;  // 16B align
  ull* h1rep = (ull*)(W + o); o += 2*(2*NREP*HID);   // u64[2][NREP][512]
  ull* h2rep = (ull*)(W + o); o += 2*(2*NREP*HID);
  (void)ws_size; (void)in_sizes; (void)n_in; (void)out_size;

  // reset tag buffers each launch (captured => every replay; kills ABA)
  hipMemsetAsync(h1rep, 0, 2ull*(2*NREP*HID)*sizeof(ull), stream);

  // u = W_v^T @ W_a[0]
  matvec<<<(128+3)/4, 256, 0, stream>>>(W_v, 128, 1, W_a, nullptr, u, 128, 128);
  // attention precompute (independent of recurrence)
  attn_kernel<<<NSTEP, 256, 0, stream>>>(V, E, u, aggr);
  // M1 = W_fc1[:,640:940] @ W_e                       [512x300]
  gemm_tiled<<<dim3(5,8), 256, 0, stream>>>(W_fc1+640, 940, W_e, 300, 0,
                                            nullptr, 0, nullptr, M1, 300, 512, 300, 300);
  // t1 = M1 @ b_fc3                                   [512]
  matvec<<<(512+3)/4, 256, 0, stream>>>(M1, 300, 0, b_fc3, nullptr, t1, 512, 300);
  // d_f_base = w_ih_f @ b_fc1 + b_ih_f                [1536]
  matvec<<<(1536+3)/4, 256, 0, stream>>>(w_ih_f, 512, 0, b_fc1, b_ih_f, dfb, 1536, 512);
  // d_f_tok = w_ih_f @ t1                             [1536]
  matvec<<<(1536+3)/4, 256, 0, stream>>>(w_ih_f, 512, 0, t1, nullptr, dft, 1536, 512);
  // d_l = w_ih_l @ b_fc2 + b_ih_l                     [1536]
  matvec<<<(1536+3)/4, 256, 0, stream>>>(w_ih_l, 512, 0, b_fc2, b_ih_l, dl, 1536, 512);
  // G1 = W_fc1[:,:512] + M1 @ W_fc3                   [512x512]
  gemm_tiled<<<dim3(8,8), 256, 0, stream>>>(M1, 300, W_fc3, 512, 0,
                                            W_fc1, 940, nullptr, G1, 512, 512, 512, 300);
  // Hf = w_ih_f @ G1                                  [1536x512]
  gemm_tiled<<<dim3(8,24), 256, 0, stream>>>(w_ih_f, 512, G1, 512, 0,
                                             nullptr, 0, nullptr, Hf, 512, 1536, 512, 512);
  // Hl = w_ih_l @ W_fc2[:,128:640]                    [1536x512]
  gemm_tiled<<<dim3(8,24), 256, 0, stream>>>(w_ih_l, 512, W_fc2+128, 640, 0,
                                             nullptr, 0, nullptr, Hl, 512, 1536, 512, 512);
  // Mv = w_ih_f @ W_fc1[:,512:640]                    [1536x128]
  gemm_tiled<<<dim3(2,24), 256, 0, stream>>>(w_ih_f, 512, W_fc1+512, 940, 0,
                                             nullptr, 0, nullptr, Mv, 128, 1536, 128, 512);
  // Ma = w_ih_l @ W_fc2[:,:128]                       [1536x128]
  gemm_tiled<<<dim3(2,24), 256, 0, stream>>>(w_ih_l, 512, W_fc2, 640, 0,
                                             nullptr, 0, nullptr, Ma, 128, 1536, 128, 512);
  // sequential recurrence: 64 persistent wgs (32 F + 32 L)
  recurrent_kernel<<<2*GWGS, 256, 0, stream>>>(Hf, w_hh_f, Hl, w_hh_l, Mv, Ma,
                                               V, aggr, dfb, dft, dl, b_hh_f, b_hh_l,
                                               h1rep, h2rep, h2all);
  // tokens = h2all @ W_fc3^T + b_fc3                  [4096x300]
  gemm_tiled<<<dim3(5,64), 256, 0, stream>>>(h2all, 512, W_fc3, 512, 1,
                                             nullptr, 0, b_fc3, out, 300, 4096, 300, 512);
}